// Round 1
// baseline (958.196 us; speedup 1.0000x reference)
//
#include <hip/hip_runtime.h>

#define B_DIM 64
#define S_DIM 784
#define T_DIM 500
#define N_DIM 1024
#define TP    522
#define KS    21
#define THETA 80
#define NCHUNK 8
#define CH    66

// RESP[w][j] = min(j+1, max(w + ceil((w-1-j)/2), 0)) for j=0..20 (time-causal response)
constexpr int RESP[8][21] = {
  {0,0,0,0,0,0,0,0,0,0,0,0,0,0,0,0,0,0,0,0,0},
  {1,1,0,0,0,0,0,0,0,0,0,0,0,0,0,0,0,0,0,0,0},
  {1,2,2,1,1,0,0,0,0,0,0,0,0,0,0,0,0,0,0,0,0},
  {1,2,3,3,2,2,1,1,0,0,0,0,0,0,0,0,0,0,0,0,0},
  {1,2,3,4,4,3,3,2,2,1,1,0,0,0,0,0,0,0,0,0,0},
  {1,2,3,4,5,5,4,4,3,3,2,2,1,1,0,0,0,0,0,0,0},
  {1,2,3,4,5,6,6,5,5,4,4,3,3,2,2,1,1,0,0,0,0},
  {1,2,3,4,5,6,7,7,6,6,5,5,4,4,3,3,2,2,1,1,0},
};

// ---- K1: transpose weights [n][s] int32 -> [s][n] uint8 (coalesced per-spike gathers)
__global__ void k_wt(const int* __restrict__ w, unsigned char* __restrict__ wt8) {
  int idx = blockIdx.x * 256 + threadIdx.x;  // over S*N
  if (idx >= S_DIM * N_DIM) return;
  int s = idx >> 10, n = idx & 1023;
  wt8[idx] = (unsigned char)w[n * S_DIM + s];
}

// ---- K2: pack spikes into bitmask [b][t][32 words]; mask pre-zeroed via memset
__global__ void k_mask(const float* __restrict__ x, unsigned* __restrict__ mask) {
  int idx = blockIdx.x * 256 + threadIdx.x;
  if (idx >= B_DIM * S_DIM * T_DIM) return;
  if (x[idx] != 0.0f) {
    int t = idx % T_DIM;
    int s = (idx / T_DIM) % S_DIM;
    int b = idx / (S_DIM * T_DIM);
    atomicOr(&mask[(b * T_DIM + t) * 32 + (s >> 5)], 1u << (s & 31));
  }
}

// ---- K3: fused sparse conv + per-(b,t') argmax. One block = (b, time-chunk),
//          one thread = one neuron. Ring of 22 partial potentials in registers.
__global__ void __launch_bounds__(1024)
k_main(const unsigned char* __restrict__ wt8,
       const unsigned* __restrict__ mask,
       unsigned* __restrict__ red) {
  __shared__ int ls_list[2][S_DIM];   // pre-shifted (s<<10)
  __shared__ int ls_cnt[2];
  __shared__ unsigned ls_max[2][16];

  const int tid = threadIdx.x;
  const int lane = tid & 63, wid = tid >> 6;
  const int b = blockIdx.y;
  const int lo = blockIdx.x * CH;            // first t' emitted
  const int hi = min(TP - 1, lo + CH - 1);   // last t' emitted
  const int t0 = max(0, lo - KS);            // warm-up start

  if (tid == 0) { ls_cnt[0] = 0; ls_cnt[1] = 0; }
  __syncthreads();

  int ring[KS + 1];  // ring[i] = partial pot[t + i]
  #pragma unroll
  for (int i = 0; i <= KS; ++i) ring[i] = 0;

  for (int t = t0; t <= hi; ++t) {
    const int p = t & 1;
    const bool emit = (t >= lo);
    const bool has_in = (t < T_DIM);

    // ---- Phase A: wave-level argmax of completed pot[t] + spike-list build (wave 0)
    if (emit) {
      unsigned key = ((unsigned)ring[0] << 10) | (unsigned)(1023 - tid);
      #pragma unroll
      for (int off = 32; off > 0; off >>= 1) {
        unsigned o = __shfl_xor(key, off);
        key = key > o ? key : o;
      }
      if (lane == 0) ls_max[p][wid] = key;
    }
    if (has_in && tid < 32) {
      unsigned word = mask[(b * T_DIM + t) * 32 + tid];
      while (word) {
        int bit = __ffs(word) - 1;
        word &= word - 1;
        int pos = atomicAdd(&ls_cnt[p], 1);
        ls_list[p][pos] = ((tid << 5) | bit) << 10;
      }
    }
    __syncthreads();

    // ---- Phase B: cross-wave argmax finish; per-thread spike accumulation
    if (emit && tid < 16) {
      unsigned k2 = ls_max[p][tid];
      #pragma unroll
      for (int off = 8; off > 0; off >>= 1) {
        unsigned o = __shfl_xor(k2, off);
        k2 = k2 > o ? k2 : o;
      }
      if (tid == 0) red[b * TP + t] = k2;
    }

    if (has_in) {
      const int cnt = ls_cnt[p];
      unsigned long long c = 0;  // seven 9-bit per-weight-class counters
      int i = 0;
      for (; i + 3 < cnt; i += 4) {
        int s0 = ls_list[p][i], s1 = ls_list[p][i + 1];
        int s2 = ls_list[p][i + 2], s3 = ls_list[p][i + 3];
        unsigned w0 = wt8[s0 + tid], w1 = wt8[s1 + tid];
        unsigned w2 = wt8[s2 + tid], w3 = wt8[s3 + tid];
        c += ((1ull << (9 * w0)) >> 9) + ((1ull << (9 * w1)) >> 9)
           + ((1ull << (9 * w2)) >> 9) + ((1ull << (9 * w3)) >> 9);
      }
      for (; i < cnt; ++i) {
        unsigned w0 = wt8[ls_list[p][i] + tid];
        c += (1ull << (9 * w0)) >> 9;
      }
      // apply response table: spikes at tau=t feed pot[t+1+j] = ring[1+j]
      #pragma unroll
      for (int w = 1; w <= 7; ++w) {
        int cw = (int)((c >> (9 * (w - 1))) & 511);
        #pragma unroll
        for (int j = 0; j < 21; ++j) {
          if (RESP[w][j]) ring[j + 1] += cw * RESP[w][j];
        }
      }
      if (tid == 0) ls_cnt[1 - p] = 0;  // wave0-ordered reset for iter t+2
    }

    // shift ring (static indices, stays in VGPRs)
    #pragma unroll
    for (int i = 0; i < KS; ++i) ring[i] = ring[i + 1];
    ring[KS] = 0;
  }
}

// ---- K4: sequential winner-take-all scan (dep dynamics), one thread per batch
__global__ void k_scan(const unsigned* __restrict__ red, int* __restrict__ out) {
  int b = threadIdx.x;
  if (b >= B_DIM) return;
  int dep = 0;
  for (int t = 0; t < TP; ++t) {
    unsigned key = red[b * TP + t];
    int val = (int)(key >> 10);
    int idx = 1023 - (int)(key & 1023);
    bool cond = (val > THETA) && (dep == 0);
    if (cond) out[(b * N_DIM + idx) * TP + t] = 1;
    dep = dep + (cond ? 22 : 0) - 1;  // FODEP+1 = 22
    if (dep < 0) dep = 0;
  }
}

extern "C" void kernel_launch(void* const* d_in, const int* in_sizes, int n_in,
                              void* d_out, int out_size, void* d_ws, size_t ws_size,
                              hipStream_t stream) {
  const float* x = (const float*)d_in[0];
  const int* wgt = (const int*)d_in[1];
  int* out = (int*)d_out;

  // workspace layout
  unsigned char* wt8 = (unsigned char*)d_ws;                                // 802,816 B
  unsigned* mask = (unsigned*)((char*)d_ws + 802816);                       // 4,096,000 B
  unsigned* red  = (unsigned*)((char*)d_ws + 802816 + 4096000);             // 133,632 B

  hipMemsetAsync(d_out, 0, (size_t)out_size * sizeof(int), stream);
  hipMemsetAsync(mask, 0, (size_t)B_DIM * T_DIM * 32 * sizeof(unsigned), stream);

  k_wt<<<(S_DIM * N_DIM + 255) / 256, 256, 0, stream>>>(wgt, wt8);
  k_mask<<<(B_DIM * S_DIM * T_DIM + 255) / 256, 256, 0, stream>>>(x, mask);
  k_main<<<dim3(NCHUNK, B_DIM), 1024, 0, stream>>>(wt8, mask, red);
  k_scan<<<1, 64, 0, stream>>>(red, out);
}

// Round 2
// 684.243 us; speedup vs baseline: 1.4004x; 1.4004x over previous
//
#include <hip/hip_runtime.h>

#define B_DIM 64
#define S_DIM 784
#define T_DIM 500
#define N_DIM 1024
#define TP    522
#define KS    21
#define THETA 80
#define NCHUNK 8
#define CH    66
#define LISTCAP 128

// ---- K1: wt9[s][n] = w ? 9*(w-1) : 63 (shift amount for 64-bit class counters);
//          also zero the per-(b,t) list counters.
__global__ void k_prep(const int* __restrict__ w, unsigned char* __restrict__ wt9,
                       unsigned* __restrict__ gcnt) {
  unsigned idx = blockIdx.x * 256 + threadIdx.x;
  if (idx < S_DIM * N_DIM) {
    unsigned s = idx >> 10, n = idx & 1023;
    int wv = w[n * S_DIM + s];
    wt9[idx] = wv ? (unsigned char)(9 * (wv - 1)) : (unsigned char)63;
  }
  if (idx < B_DIM * T_DIM) gcnt[idx] = 0;
}

// ---- K2: build per-(b,t) spike lists in global memory (order irrelevant: sums commute)
__global__ void k_lists(const float* __restrict__ x, unsigned* __restrict__ gcnt,
                        unsigned short* __restrict__ glist) {
  unsigned idx = blockIdx.x * 256 + threadIdx.x;
  if (idx >= B_DIM * S_DIM * T_DIM) return;
  if (x[idx] != 0.0f) {
    unsigned t = idx % T_DIM;
    unsigned s = (idx / T_DIM) % S_DIM;
    unsigned b = idx / (S_DIM * T_DIM);
    unsigned cell = b * T_DIM + t;
    unsigned pos = atomicAdd(&gcnt[cell], 1u);
    if (pos < LISTCAP) glist[cell * LISTCAP + pos] = (unsigned short)s;
  }
}

// ---- K3: barrier-free fused sparse conv + argmax. One block = (b, time-chunk),
//          one thread = one neuron; 22-deep register ring of partial potentials.
__global__ void __launch_bounds__(1024, 8)
k_main(const unsigned char* __restrict__ wt9,
       const unsigned* __restrict__ gcnt,
       const unsigned short* __restrict__ glist,
       unsigned* __restrict__ red) {
  __shared__ unsigned short s_list[87][LISTCAP];
  __shared__ int s_cnt[87];
  __shared__ unsigned smax[CH];

  const int tid = threadIdx.x;
  const int b = blockIdx.y;
  const int lo = blockIdx.x * CH;
  const int hi = min(TP - 1, lo + CH - 1);
  const int t0 = max(0, lo - KS);
  const int n_emit = hi - lo + 1;
  const int nt_in = min(hi, T_DIM - 1) - t0 + 1;

  // ---- prologue: stage this block's spike lists + counters into LDS
  const unsigned cell0 = (unsigned)b * T_DIM + (unsigned)t0;
  for (int i = tid; i < nt_in; i += 1024)
    s_cnt[i] = min((int)gcnt[cell0 + i], LISTCAP);
  {
    const unsigned* src = (const unsigned*)(glist + (size_t)cell0 * LISTCAP);
    unsigned* dst = (unsigned*)&s_list[0][0];
    const int nw = nt_in * (LISTCAP / 2);
    for (int i = tid; i < nw; i += 1024) dst[i] = src[i];
  }
  for (int i = tid; i < n_emit; i += 1024) smax[i] = 0u;
  __syncthreads();

  int ring[KS + 1];
  #pragma unroll
  for (int i = 0; i <= KS; ++i) ring[i] = 0;

  const unsigned invn = (unsigned)(1023 - tid);

  for (int t = t0; t <= hi; ++t) {
    // per-t argmax: wave-local butterfly, then one LDS atomicMax per wave (no barrier)
    if (t >= lo) {
      unsigned key = ((unsigned)ring[0] << 10) | invn;
      #pragma unroll
      for (int off = 32; off > 0; off >>= 1) {
        unsigned o = __shfl_xor(key, off, 64);
        key = key > o ? key : o;
      }
      if ((tid & 63) == 0) atomicMax(&smax[t - lo], key);
    }

    if (t < T_DIM) {
      const int li = t - t0;
      const int cnt = __builtin_amdgcn_readfirstlane(s_cnt[li]);
      const unsigned short* lp = &s_list[li][0];
      unsigned long long ca = 0, cb = 0;   // seven 9-bit class counters (bit63 = w0 garbage)
      int i = 0;
      for (; i + 1 < cnt; i += 2) {
        unsigned ia = ((unsigned)lp[i] << 10) + tid;
        unsigned ib = ((unsigned)lp[i + 1] << 10) + tid;
        ca += 1ull << wt9[ia];
        cb += 1ull << wt9[ib];
      }
      if (i < cnt) ca += 1ull << wt9[((unsigned)lp[i] << 10) + tid];
      const unsigned long long c = ca + cb;

      const int c1 = (int)(c & 511), c2 = (int)((c >> 9) & 511), c3 = (int)((c >> 18) & 511),
                c4 = (int)((c >> 27) & 511), c5 = (int)((c >> 36) & 511),
                c6 = (int)((c >> 45) & 511), c7 = (int)((c >> 54) & 511);
      // response-table application as running-delta adds (63 single-slot ops, no muls):
      const int S7 = c7, S6 = S7 + c6, S5 = S6 + c5, S4 = S5 + c4,
                S3 = S4 + c3, S2 = S3 + c2, S1 = S2 + c1;
      const int O1 = c1, O3 = O1 + c3, O5 = O3 + c5, O7 = O5 + c7;
      const int E2 = c2, E4 = E2 + c4, E6 = E4 + c6;
      const int O31 = O3 - O1, O51 = O5 - O1, O71 = O7 - O1,
                O73 = O7 - O3, O75 = O7 - O5;
      const int E62 = E6 - E2, E64 = E6 - E4;
      int acc = S1;        ring[1]  += acc;
      acc += S2;           ring[2]  += acc;
      acc += S3 - O1;      ring[3]  += acc;
      acc += S4 - E2;      ring[4]  += acc;
      acc += S5 - O31;     ring[5]  += acc;
      acc += S6 - E4;      ring[6]  += acc;
      acc += S7 - O51;     ring[7]  += acc;
      acc -= E62;          ring[8]  += acc;
      acc -= O71;          ring[9]  += acc;
      acc -= E62;          ring[10] += acc;
      acc -= O73;          ring[11] += acc;
      acc -= E62;          ring[12] += acc;
      acc -= O73;          ring[13] += acc;
      acc -= E64;          ring[14] += acc;
      acc -= O73;          ring[15] += acc;
      acc -= E64;          ring[16] += acc;
      acc -= O75;          ring[17] += acc;
      acc -= E64;          ring[18] += acc;
      acc -= O75;          ring[19] += acc;
                           ring[20] += acc;
      acc -= O75;          ring[21] += acc;
    }

    #pragma unroll
    for (int i = 0; i < KS; ++i) ring[i] = ring[i + 1];
    ring[KS] = 0;
  }

  __syncthreads();
  for (int i = tid; i < n_emit; i += 1024)
    red[(unsigned)b * TP + (unsigned)(lo + i)] = smax[i];
}

// ---- K4: winner-take-all dep scan; 6-wide load batching to hide L2 latency
__global__ void k_scan(const unsigned* __restrict__ red, int* __restrict__ out) {
  int b = threadIdx.x;
  if (b >= B_DIM) return;
  int dep = 0;
  for (int base = 0; base < TP; base += 6) {   // 522 = 87*6
    unsigned buf[6];
    #pragma unroll
    for (int k = 0; k < 6; ++k) buf[k] = red[b * TP + base + k];
    #pragma unroll
    for (int k = 0; k < 6; ++k) {
      unsigned key = buf[k];
      int val = (int)(key >> 10);
      bool cond = (val > THETA) && (dep == 0);
      if (cond) {
        int idx = 1023 - (int)(key & 1023);
        out[(b * N_DIM + idx) * TP + base + k] = 1;
        dep = 22;  // FODEP+1
      }
      dep = max(0, dep - 1);
    }
  }
}

extern "C" void kernel_launch(void* const* d_in, const int* in_sizes, int n_in,
                              void* d_out, int out_size, void* d_ws, size_t ws_size,
                              hipStream_t stream) {
  const float* x = (const float*)d_in[0];
  const int* wgt = (const int*)d_in[1];
  int* out = (int*)d_out;

  // workspace layout (total ~9.26 MB)
  unsigned char* wt9    = (unsigned char*)d_ws;                           // 802,816 B
  unsigned* gcnt        = (unsigned*)((char*)d_ws + 802816);              // 128,000 B
  unsigned short* glist = (unsigned short*)((char*)d_ws + 930816);        // 8,192,000 B
  unsigned* red         = (unsigned*)((char*)d_ws + 9122816);             // 133,632 B

  hipMemsetAsync(d_out, 0, (size_t)out_size * sizeof(int), stream);
  k_prep<<<3136, 256, 0, stream>>>(wgt, wt9, gcnt);
  k_lists<<<(B_DIM * S_DIM * T_DIM + 255) / 256, 256, 0, stream>>>(x, gcnt, glist);
  k_main<<<dim3(NCHUNK, B_DIM), 1024, 0, stream>>>(wt9, gcnt, glist, red);
  k_scan<<<1, 64, 0, stream>>>(red, out);
}